// Round 1
// baseline (261.320 us; speedup 1.0000x reference)
//
#include <hip/hip_runtime.h>
#include <stdint.h>

#define Bq   4
#define Nseq 2048
#define NH   16
#define HD   64
#define DIMD 1024

typedef float  f32x4   __attribute__((ext_vector_type(4)));
typedef float  f32x16  __attribute__((ext_vector_type(16)));
typedef __bf16 bf16x8  __attribute__((ext_vector_type(8)));
typedef short  s16x4   __attribute__((ext_vector_type(4)));

typedef __attribute__((address_space(1))) void as1_void;
typedef __attribute__((address_space(3))) void as3_void;

static __device__ __forceinline__ uint16_t f2bf(float f) {
    uint32_t u = __builtin_bit_cast(uint32_t, f);
    u += 0x7fffu + ((u >> 16) & 1u);          // RNE
    return (uint16_t)(u >> 16);
}

// truncation-pack two fp32 -> packed bf16x2 (p>=0, 1-ulp bias, cancels in p/l)
static __device__ __forceinline__ uint32_t pk2(float a, float b) {
    uint32_t ua = __builtin_bit_cast(uint32_t, a);
    uint32_t ub = __builtin_bit_cast(uint32_t, b);
    return (ua >> 16) | (ub & 0xffff0000u);
}

static __device__ __forceinline__ void asyncLoad16(const uint16_t* g, uint16_t* l) {
    __builtin_amdgcn_global_load_lds((as1_void*)g, (as3_void*)l, 16, 0, 0);
}

static __device__ __forceinline__ void storeOut(float* p, float v)    { *p = v; }
static __device__ __forceinline__ void storeOut(uint16_t* p, float v) { *p = f2bf(v); }

// ---------------------------------------------------------------------------
// cast fp32 -> bf16 : x (8388608) then Wq,Wk,Wv,Wo (4 x 1048576), dst contiguous
// Wq is pre-scaled by SCALE*log2(e) so attention can use exp2 on raw QK dots.
// ---------------------------------------------------------------------------
__global__ void cast_all(const float* __restrict__ x,
                         const float* __restrict__ wq, const float* __restrict__ wk,
                         const float* __restrict__ wv, const float* __restrict__ wo,
                         uint16_t* __restrict__ dst) {
    size_t i = ((size_t)blockIdx.x * blockDim.x + threadIdx.x) * 4;  // elem idx
    const float* src; size_t off; float scale = 1.0f;
    if (i < 8388608) { src = x; off = i; }
    else {
        size_t wI = i - 8388608;
        size_t wi = wI >> 20;
        off = wI & 1048575;
        src = (wi == 0) ? wq : (wi == 1) ? wk : (wi == 2) ? wv : wo;
        if (wi == 0) scale = 0.18033688011112042f;   // (1/sqrt(64)) * log2(e)
    }
    float4 v = *(const float4*)(src + off);
    ushort4 o;
    o.x = f2bf(v.x * scale); o.y = f2bf(v.y * scale);
    o.z = f2bf(v.z * scale); o.w = f2bf(v.w * scale);
    *(ushort4*)(dst + i) = o;
}

// ---------------------------------------------------------------------------
// QKV GEMM, 8-phase 256x256 schedule (T2+T3+T4+T5):
//   C[m][n] = sum_k A[m][k] * W[n][k], K=1024, BK=64, 512 thr = 8 waves (2Mx4N).
// Wave tile 128x64 = 4x2 tiles of 32x32 (8 mfma_32x32x16 per phase).
// LDS 128 KiB: whole-K-tile double buffer, chunk^row&7 swizzle (same scheme as
// the verified 128^2 kernel; 2-way max on b128 reads).
// Staging of tile t+1 spread over phases (sets: B0B1 | B2B3,A0,A2 | A1,A3 | -),
// counted waits only: vmcnt(6) @p2-end (forces A1,A3 of CURRENT tile),
// vmcnt(2) @p4-end (forces everything of t+1 except A1,A3). Never 0 mid-loop.
// Raw s_barrier via asm (no compiler vmcnt(0) drain), setprio(1) around MFMA.
// Liveness: stages only touch buf^1, read fully one tile earlier => race-free
// with one barrier pair per phase.
// Grid (32,12): xcd = linear%8 = x%8 -> each A-panel pinned to one XCD's L2.
// sec = y>>2 in {Q,K,V}; V (sec 2) written transposed vt[(b*16+h)*64+d][tok].
// ---------------------------------------------------------------------------
#define BAR()    asm volatile("s_barrier" ::: "memory")
#define VMBAR(N) asm volatile("s_waitcnt vmcnt(" #N ")\n\ts_barrier" ::: "memory")

__global__ __launch_bounds__(512, 2) void gemm256_qkv(
    const uint16_t* __restrict__ A, const uint16_t* __restrict__ W0,
    uint16_t* __restrict__ C0, uint16_t* __restrict__ vtb)
{
    __shared__ __align__(16) uint16_t As[2][16384];   // 256 x 64 bf16 per buf
    __shared__ __align__(16) uint16_t Bs[2][16384];

    const int t = threadIdx.x, lane = t & 63, w = t >> 6;
    const int wm = w >> 2, wn = w & 3;                // 2 x 4 wave grid
    const int ml = lane & 31, half = lane >> 5;

    const int m0  = blockIdx.x * 256;
    const int sec = blockIdx.y >> 2;                  // 0=Q 1=K 2=V
    const int n0  = (blockIdx.y & 3) * 256;
    const uint16_t* __restrict__ Wp = W0 + (size_t)sec * 1048576;

    // staging: 64-row set per global_load_lds issue (512 thr x 16B = 8 KB)
    const int srow = t >> 3;                          // row within set
    const int sg   = (t & 7) ^ (srow & 7);            // pre-swizzled chunk
    const size_t aOff = (size_t)(m0 + srow) * DIMD + sg * 8;
    const size_t bOff = (size_t)(n0 + srow) * DIMD + sg * 8;
    const int slot = w * 512;                         // wave-uniform LDS base

#define SA(set_, buf_, kk_) asyncLoad16(A  + aOff + (size_t)(set_)*64*DIMD + (kk_), \
                                        &As[buf_][(set_)*4096 + slot])
#define SB(set_, buf_, kk_) asyncLoad16(Wp + bOff + (size_t)(set_)*64*DIMD + (kk_), \
                                        &Bs[buf_][(set_)*4096 + slot])

    // ---- prologue: stage K-tile 0 into buf0; A sets 1,3 issued LAST so the
    //      steady-state vmcnt counting holds from iteration 0.
    SB(0,0,0); SB(1,0,0); SB(2,0,0); SB(3,0,0);
    SA(0,0,0); SA(2,0,0);
    SA(1,0,0); SA(3,0,0);
    VMBAR(2);

    // per-thread constant LDS read offsets
    int pos8[4];
    #pragma unroll
    for (int s = 0; s < 4; ++s) pos8[s] = ((s*2 + half) ^ (ml & 7)) * 8;
    const int arow0 = (wm*128 + ml) * 64;
    const int brow0 = (wn*64  + ml) * 64;

    f32x16 acc[4][2] = {};

    #pragma unroll 2
    for (int kt = 0; kt < 16; ++kt) {
        const int cur = kt & 1, nxt = cur ^ 1;
        const int k1 = (kt + 1) * 64;
        const bool pf = (kt + 1 < 16);
        const uint16_t* __restrict__ Ac = As[cur];
        const uint16_t* __restrict__ Bc = Bs[cur];

        bf16x8 af[2][4], bf[2][4];

        // ---------- phase 1: (mh0, nh0); read A mt{0,1} + all B ----------
        #pragma unroll
        for (int i = 0; i < 2; ++i)
            #pragma unroll
            for (int s = 0; s < 4; ++s) {
                af[i][s] = *(const bf16x8*)(Ac + arow0 + i*2048 + pos8[s]);
                bf[i][s] = *(const bf16x8*)(Bc + brow0 + i*2048 + pos8[s]);
            }
        if (pf) { SB(0,nxt,k1); SB(1,nxt,k1); }
        BAR();
        __builtin_amdgcn_s_setprio(1);
        #pragma unroll
        for (int s = 0; s < 4; ++s) {
            acc[0][0] = __builtin_amdgcn_mfma_f32_32x32x16_bf16(af[0][s], bf[0][s], acc[0][0], 0,0,0);
            acc[1][0] = __builtin_amdgcn_mfma_f32_32x32x16_bf16(af[1][s], bf[0][s], acc[1][0], 0,0,0);
        }
        __builtin_amdgcn_s_setprio(0);
        BAR();

        // ---------- phase 2: (mh0, nh1) ----------
        if (pf) { SB(2,nxt,k1); SB(3,nxt,k1); SA(0,nxt,k1); SA(2,nxt,k1); }
        BAR();
        __builtin_amdgcn_s_setprio(1);
        #pragma unroll
        for (int s = 0; s < 4; ++s) {
            acc[0][1] = __builtin_amdgcn_mfma_f32_32x32x16_bf16(af[0][s], bf[1][s], acc[0][1], 0,0,0);
            acc[1][1] = __builtin_amdgcn_mfma_f32_32x32x16_bf16(af[1][s], bf[1][s], acc[1][1], 0,0,0);
        }
        __builtin_amdgcn_s_setprio(0);
        if (pf) { VMBAR(6); } else { VMBAR(0); }   // force A1,A3(cur) landed

        // ---------- phase 3: (mh1, nh0); read A mt{2,3} ----------
        #pragma unroll
        for (int i = 0; i < 2; ++i)
            #pragma unroll
            for (int s = 0; s < 4; ++s)
                af[i][s] = *(const bf16x8*)(Ac + arow0 + 4096 + i*2048 + pos8[s]);
        if (pf) { SA(1,nxt,k1); SA(3,nxt,k1); }
        BAR();
        __builtin_amdgcn_s_setprio(1);
        #pragma unroll
        for (int s = 0; s < 4; ++s) {
            acc[2][0] = __builtin_amdgcn_mfma_f32_32x32x16_bf16(af[0][s], bf[0][s], acc[2][0], 0,0,0);
            acc[3][0] = __builtin_amdgcn_mfma_f32_32x32x16_bf16(af[1][s], bf[0][s], acc[3][0], 0,0,0);
        }
        __builtin_amdgcn_s_setprio(0);
        BAR();

        // ---------- phase 4: (mh1, nh1) ----------
        __builtin_amdgcn_s_setprio(1);
        #pragma unroll
        for (int s = 0; s < 4; ++s) {
            acc[2][1] = __builtin_amdgcn_mfma_f32_32x32x16_bf16(af[0][s], bf[1][s], acc[2][1], 0,0,0);
            acc[3][1] = __builtin_amdgcn_mfma_f32_32x32x16_bf16(af[1][s], bf[1][s], acc[3][1], 0,0,0);
        }
        __builtin_amdgcn_s_setprio(0);
        if (pf) { VMBAR(2); } else { BAR(); }      // force all of t+1 but A1,A3
    }

#undef SA
#undef SB

    // ---- epilogue: C/D 32x32 layout col=lane&31, row=(r&3)+8*(r>>2)+4*half ----
    if (sec == 2) {
        #pragma unroll
        for (int mt = 0; mt < 4; ++mt)
            #pragma unroll
            for (int nt = 0; nt < 2; ++nt) {
                int colg = n0 + wn*64 + nt*32 + ml;              // dim
                int hh = colg >> 6, dd = colg & 63;
                #pragma unroll
                for (int g = 0; g < 4; ++g) {
                    int rowg = m0 + wm*128 + mt*32 + 8*g + 4*half; // token (+reg&3)
                    int bb = rowg >> 11, nn = rowg & 2047;
                    ushort4 o4;
                    o4.x = f2bf(acc[mt][nt][4*g + 0]);
                    o4.y = f2bf(acc[mt][nt][4*g + 1]);
                    o4.z = f2bf(acc[mt][nt][4*g + 2]);
                    o4.w = f2bf(acc[mt][nt][4*g + 3]);
                    *(ushort4*)(vtb + ((size_t)((bb*NH + hh)*HD + dd))*Nseq + nn) = o4;
                }
            }
    } else {
        uint16_t* C = C0 + (size_t)sec * 8388608;
        #pragma unroll
        for (int mt = 0; mt < 4; ++mt)
            #pragma unroll
            for (int nt = 0; nt < 2; ++nt) {
                int col = n0 + wn*64 + nt*32 + ml;
                #pragma unroll
                for (int r = 0; r < 16; ++r) {
                    int row = m0 + wm*128 + mt*32 + (r & 3) + 8*(r >> 2) + 4*half;
                    C[(size_t)row * DIMD + col] = f2bf(acc[mt][nt][r]);
                }
            }
    }
}

// ---------------------------------------------------------------------------
// GEMM  C[m][n] = sum_k A[m][k] * W[n][k]   (B^T layout, both row-major over K)
// 128x128 tile, BK=64, 256 thr = 4 waves (2x2) -- retained for the output
// projection (N=1024 would leave half the CUs idle at 256^2 tiling).
// ---------------------------------------------------------------------------
template <typename OutT>
__global__ __launch_bounds__(256) void gemm_bt(
    const uint16_t* __restrict__ A, const uint16_t* __restrict__ W0,
    OutT* __restrict__ C0, int K, int Nld, int blocksPerSec,
    size_t wSecStride, size_t cSecStride, uint16_t* __restrict__ vtb, int vSec)
{
    __shared__ __align__(16) uint16_t As[128*64];
    __shared__ __align__(16) uint16_t Bs[128*64];

    const int t = threadIdx.x, lane = t & 63, w = t >> 6;
    const int wr = w >> 1, wc = w & 1;
    const int half = lane >> 5, ml = lane & 31;

    const int m0  = blockIdx.x * 128;
    const int sec = blockIdx.y / blocksPerSec;
    const int n0  = (blockIdx.y % blocksPerSec) * 128;
    const uint16_t* Wp = W0 + (size_t)sec * wSecStride;
    OutT* C = C0 + (size_t)sec * cSecStride;

    int srow[4], sg[4];
    #pragma unroll
    for (int i = 0; i < 4; ++i) {
        int s = t + 256*i;
        srow[i] = s >> 3;
        sg[i]   = (s & 7) ^ (srow[i] & 7);
    }

    int arow[2], brow[2];
    #pragma unroll
    for (int i = 0; i < 2; ++i) {
        arow[i] = wr*64 + i*32 + ml;
        brow[i] = wc*64 + i*32 + ml;
    }

    f32x16 acc[2][2] = {};

    for (int k0 = 0; k0 < K; k0 += 64) {
        __syncthreads();
        #pragma unroll
        for (int i = 0; i < 4; ++i) {
            asyncLoad16(A  + (size_t)(m0 + srow[i])*K + k0 + sg[i]*8,
                        As + (size_t)(w*64 + 256*i)*8);
            asyncLoad16(Wp + (size_t)(n0 + srow[i])*K + k0 + sg[i]*8,
                        Bs + (size_t)(w*64 + 256*i)*8);
        }
        __syncthreads();

        #pragma unroll
        for (int s = 0; s < 4; ++s) {            // k-step of 16
            const int chunk = s*2 + half;
            bf16x8 af[2], bfr[2];
            #pragma unroll
            for (int i = 0; i < 2; ++i) {
                int m = arow[i];
                af[i]  = *(const bf16x8*)(As + (size_t)(m*8 + (chunk ^ (m & 7)))*8);
                int n = brow[i];
                bfr[i] = *(const bf16x8*)(Bs + (size_t)(n*8 + (chunk ^ (n & 7)))*8);
            }
            #pragma unroll
            for (int mt = 0; mt < 2; ++mt)
                #pragma unroll
                for (int nt = 0; nt < 2; ++nt)
                    acc[mt][nt] = __builtin_amdgcn_mfma_f32_32x32x16_bf16(
                        af[mt], bfr[nt], acc[mt][nt], 0, 0, 0);
        }
    }

    if (vtb != nullptr && sec == vSec) {
        #pragma unroll
        for (int mt = 0; mt < 2; ++mt)
            #pragma unroll
            for (int nt = 0; nt < 2; ++nt) {
                int colg = n0 + wc*64 + nt*32 + ml;               // dim
                int hh = colg >> 6, dd = colg & 63;
                #pragma unroll
                for (int g = 0; g < 4; ++g) {
                    int rowg = m0 + wr*64 + mt*32 + 8*g + 4*half; // token (+reg&3)
                    int bb = rowg >> 11, nn = rowg & 2047;
                    ushort4 o4;
                    o4.x = f2bf(acc[mt][nt][4*g + 0]);
                    o4.y = f2bf(acc[mt][nt][4*g + 1]);
                    o4.z = f2bf(acc[mt][nt][4*g + 2]);
                    o4.w = f2bf(acc[mt][nt][4*g + 3]);
                    *(ushort4*)(vtb + ((size_t)((bb*NH + hh)*HD + dd))*Nseq + nn) = o4;
                }
            }
    } else {
        #pragma unroll
        for (int mt = 0; mt < 2; ++mt)
            #pragma unroll
            for (int nt = 0; nt < 2; ++nt) {
                int col = n0 + wc*64 + nt*32 + ml;
                #pragma unroll
                for (int r = 0; r < 16; ++r) {
                    int row = m0 + wr*64 + mt*32 + (r & 3) + 8*(r >> 2) + 4*half;
                    storeOut(&C[(size_t)row * Nld + col], acc[mt][nt][r]);
                }
            }
    }
}

// ---------------------------------------------------------------------------
// Flash attention, causal, no-max online softmax, S^T formulation:
//   S^T = K.Q^T  -> P^T in registers is the B-operand of mfma 16x16x16bf16_1k
//   -> O^T = V^T.P^T, no P LDS round-trip.
// ---------------------------------------------------------------------------
__global__ __launch_bounds__(256, 4) void attn(
    const uint16_t* __restrict__ Q, const uint16_t* __restrict__ K,
    const uint16_t* __restrict__ Vt, uint16_t* __restrict__ O)
{
    __shared__ __align__(16) uint16_t Kb[2][64*64];   // 16 KB (also Q scratch)
    __shared__ __align__(16) uint16_t Vb[2][64*64];   // 16 KB (V^T tiles, rows=d)

    const int t = threadIdx.x, lane = t & 63, w = t >> 6;
    const int quad = lane >> 4, c = lane & 15;
    const int y = blockIdx.y;
    const int qi = (y < 4) ? (15 - y) : (y < 8) ? (y + 4) : (y < 12) ? (y - 4) : (15 - y);
    const int q0 = qi * 128;
    const int bh = blockIdx.x, b = bh >> 4, h = bh & 15;
    const size_t tokBase = (size_t)b * Nseq;
    const int hcol = h * HD;
    uint16_t* Qs = (uint16_t*)Kb;                    // 16 KB scratch

    #define STAGE_KV(k0_, buf_)                                             \
        _Pragma("unroll")                                                    \
        for (int i = 0; i < 2; ++i) {                                        \
            int s = t + 256*i;                                               \
            int row = s >> 3, gg = (s & 7) ^ (row & 7);                      \
            asyncLoad16(K + (tokBase + (k0_) + row)*DIMD + hcol + gg*8,      \
                        Kb[buf_] + (size_t)(w*64 + 256*i)*8);                \
            asyncLoad16(Vt + ((size_t)bh*HD + row)*Nseq + (k0_) + gg*8,      \
                        Vb[buf_] + (size_t)(w*64 + 256*i)*8);                \
        }

    // ---- stage Q (128x64) through scratch, grab fragments, then free it ----
    #pragma unroll
    for (int i = 0; i < 4; ++i) {
        int s = t + 256*i;
        int row = s >> 3, gg = (s & 7) ^ (row & 7);
        asyncLoad16(Q + (tokBase + q0 + row)*DIMD + hcol + gg*8,
                    Qs + (size_t)(w*64 + 256*i)*8);
    }
    __syncthreads();                                  // Q landed
    bf16x8 qf[2][2];
    #pragma unroll
    for (int qt = 0; qt < 2; ++qt)
        #pragma unroll
        for (int ks = 0; ks < 2; ++ks) {
            int row = w*32 + qt*16 + c;
            int pos = (ks*4 + quad) ^ (row & 7);
            qf[qt][ks] = *(const bf16x8*)(Qs + (size_t)(row*8 + pos)*8);
        }
    __syncthreads();                                  // all reads done, scratch free
    STAGE_KV(0, 0);

    const int wrow0 = q0 + w*32;
    const int end = 2*qi + 2;
    f32x4  o[2][4] = {};
    float  l_lane[2] = {0.f, 0.f};

    for (int kt = 0; kt < end; ++kt) {
        const int cur = kt & 1, nxt = cur ^ 1;
        const int k0 = kt * 64;
        __syncthreads();              // buf[cur] ready; buf[nxt] free to fill

        if (kt + 1 < end) { STAGE_KV((kt+1)*64, nxt); }

        if (k0 > wrow0 + 31) continue;     // wave fully above diagonal

        const uint16_t* Ks = Kb[cur];
        const uint16_t* Vs = Vb[cur];

        // ---- S^T = K.Q^T : C-layout row = kv (quad*4+r), col = q (c) ----
        f32x4 sv[2][4] = {};
        #pragma unroll
        for (int nt = 0; nt < 4; ++nt)
            #pragma unroll
            for (int ks = 0; ks < 2; ++ks) {
                int row = nt*16 + c;
                int pos = (ks*4 + quad) ^ (row & 7);
                bf16x8 kf = *(const bf16x8*)(Ks + (size_t)(row*8 + pos)*8);
                sv[0][nt] = __builtin_amdgcn_mfma_f32_16x16x32_bf16(kf, qf[0][ks], sv[0][nt], 0, 0, 0);
                sv[1][nt] = __builtin_amdgcn_mfma_f32_16x16x32_bf16(kf, qf[1][ks], sv[1][nt], 0, 0, 0);
            }

        // ---- causal mask (diagonal tiles only; kv > q -> -inf) ----
        if (k0 + 63 > wrow0) {
            #pragma unroll
            for (int qt = 0; qt < 2; ++qt)
                #pragma unroll
                for (int nt = 0; nt < 4; ++nt)
                    #pragma unroll
                    for (int r = 0; r < 4; ++r) {
                        int kvg = k0 + nt*16 + quad*4 + r;
                        int qg  = wrow0 + qt*16 + c;
                        if (kvg > qg) sv[qt][nt][r] = -340.0f;
                    }
        }

        // ---- p = exp2(s); row-sum per lane; pack P^T as B-frags ----
        s16x4 pb[2][4];
        #pragma unroll
        for (int qt = 0; qt < 2; ++qt)
            #pragma unroll
            for (int nt = 0; nt < 4; ++nt) {
                float p0 = __builtin_amdgcn_exp2f(sv[qt][nt][0]);
                float p1 = __builtin_amdgcn_exp2f(sv[qt][nt][1]);
                float p2 = __builtin_amdgcn_exp2f(sv[qt][nt][2]);
                float p3 = __builtin_amdgcn_exp2f(sv[qt][nt][3]);
                l_lane[qt] += (p0 + p1) + (p2 + p3);
                union { uint32_t u[2]; s16x4 v; } pu;
                pu.u[0] = pk2(p0, p1);
                pu.u[1] = pk2(p2, p3);
                pb[qt][nt] = pu.v;
            }

        // ---- O^T += V^T.P^T  (K=16 steps; A=V^T rows from LDS b64) ----
        #pragma unroll
        for (int s4 = 0; s4 < 4; ++s4)
            #pragma unroll
            for (int dt = 0; dt < 4; ++dt) {
                int row = dt*16 + c;                    // d
                int chunk = s4*2 + (quad >> 1);
                int pos = chunk ^ (row & 7);
                s16x4 vf = *(const s16x4*)(Vs + (size_t)(row*8 + pos)*8 + (quad & 1)*4);
                o[0][dt] = __builtin_amdgcn_mfma_f32_16x16x16bf16_1k(vf, pb[0][s4], o[0][dt], 0, 0, 0);
                o[1][dt] = __builtin_amdgcn_mfma_f32_16x16x16bf16_1k(vf, pb[1][s4], o[1][dt], 0, 0, 0);
            }
    }

    // ---- epilogue: reduce l over quads, scale, store O^T packed ----
    #pragma unroll
    for (int qt = 0; qt < 2; ++qt) {
        float l = l_lane[qt];
        l += __shfl_xor(l, 16);
        l += __shfl_xor(l, 32);
        float inv = 1.0f / l;
        int tok = (int)(q0 + w*32 + qt*16 + c);
        #pragma unroll
        for (int dt = 0; dt < 4; ++dt) {
            ushort4 o4;
            o4.x = f2bf(o[qt][dt][0] * inv);
            o4.y = f2bf(o[qt][dt][1] * inv);
            o4.z = f2bf(o[qt][dt][2] * inv);
            o4.w = f2bf(o[qt][dt][3] * inv);
            *(ushort4*)(O + (tokBase + tok)*DIMD + hcol + dt*16 + quad*4) = o4;
        }
    }
    #undef STAGE_KV
}

// ---------------------------------------------------------------------------
extern "C" void kernel_launch(void* const* d_in, const int* in_sizes, int n_in,
                              void* d_out, int out_size, void* d_ws, size_t ws_size,
                              hipStream_t stream) {
    const float* x  = (const float*)d_in[0];
    // d_in[1] = causal tril mask, deterministic -> handled analytically
    const float* Wq = (const float*)d_in[2];
    const float* Wk = (const float*)d_in[3];
    const float* Wv = (const float*)d_in[4];
    const float* Wo = (const float*)d_in[5];

    uint16_t* ws  = (uint16_t*)d_ws;
    uint16_t* xb  = ws;                      // x bf16 (later reused as attn out)
    uint16_t* wqb = ws + 8388608;            // Wq,Wk,Wv,Wo bf16 contiguous
    uint16_t* wob = wqb + 3*1048576;
    uint16_t* qb  = ws + 12582912;           // Q
    uint16_t* kb  = qb + 8388608;            // K
    uint16_t* vtb = kb + 8388608;            // V transposed per (b,h)
    uint16_t* ab  = xb;                      // attention output reuses xb

    cast_all<<<12288, 256, 0, stream>>>(x, Wq, Wk, Wv, Wo, ws);

    // QKV: 256^2 8-phase kernel; grid (m, sec*4+n): xcd = m%8 pins each
    // x-panel's A reads to one XCD's L2.
    gemm256_qkv<<<dim3(32, 12), 512, 0, stream>>>(xb, wqb, qb, vtb);

    attn<<<dim3(64, 16), 256, 0, stream>>>(qb, kb, vtb, ab);

    gemm_bt<float><<<dim3(64, 8), 256, 0, stream>>>(
        ab, wob, (float*)d_out, DIMD, DIMD, 8, (size_t)0, (size_t)0, nullptr, -1);
}

// Round 2
// 253.393 us; speedup vs baseline: 1.0313x; 1.0313x over previous
//
#include <hip/hip_runtime.h>
#include <stdint.h>

#define Bq   4
#define Nseq 2048
#define NH   16
#define HD   64
#define DIMD 1024

typedef float  f32x4   __attribute__((ext_vector_type(4)));
typedef float  f32x16  __attribute__((ext_vector_type(16)));
typedef __bf16 bf16x8  __attribute__((ext_vector_type(8)));
typedef short  s16x4   __attribute__((ext_vector_type(4)));

typedef __attribute__((address_space(1))) void as1_void;
typedef __attribute__((address_space(3))) void as3_void;

static __device__ __forceinline__ uint16_t f2bf(float f) {
    uint32_t u = __builtin_bit_cast(uint32_t, f);
    u += 0x7fffu + ((u >> 16) & 1u);          // RNE
    return (uint16_t)(u >> 16);
}

// truncation-pack two fp32 -> packed bf16x2 (p>=0, 1-ulp bias, cancels in p/l)
static __device__ __forceinline__ uint32_t pk2(float a, float b) {
    uint32_t ua = __builtin_bit_cast(uint32_t, a);
    uint32_t ub = __builtin_bit_cast(uint32_t, b);
    return (ua >> 16) | (ub & 0xffff0000u);
}

static __device__ __forceinline__ void asyncLoad16(const uint16_t* g, uint16_t* l) {
    __builtin_amdgcn_global_load_lds((as1_void*)g, (as3_void*)l, 16, 0, 0);
}

static __device__ __forceinline__ void storeOut(float* p, float v)    { *p = v; }
static __device__ __forceinline__ void storeOut(uint16_t* p, float v) { *p = f2bf(v); }

// ---------------------------------------------------------------------------
// cast fp32 -> bf16 : x (8388608) then Wq,Wk,Wv,Wo (4 x 1048576), dst contiguous
// Wq is pre-scaled by SCALE*log2(e) so attention can use exp2 on raw QK dots.
// ---------------------------------------------------------------------------
__global__ void cast_all(const float* __restrict__ x,
                         const float* __restrict__ wq, const float* __restrict__ wk,
                         const float* __restrict__ wv, const float* __restrict__ wo,
                         uint16_t* __restrict__ dst) {
    size_t i = ((size_t)blockIdx.x * blockDim.x + threadIdx.x) * 4;  // elem idx
    const float* src; size_t off; float scale = 1.0f;
    if (i < 8388608) { src = x; off = i; }
    else {
        size_t wI = i - 8388608;
        size_t wi = wI >> 20;
        off = wI & 1048575;
        src = (wi == 0) ? wq : (wi == 1) ? wk : (wi == 2) ? wv : wo;
        if (wi == 0) scale = 0.18033688011112042f;   // (1/sqrt(64)) * log2(e)
    }
    float4 v = *(const float4*)(src + off);
    ushort4 o;
    o.x = f2bf(v.x * scale); o.y = f2bf(v.y * scale);
    o.z = f2bf(v.z * scale); o.w = f2bf(v.w * scale);
    *(ushort4*)(dst + i) = o;
}

#define BAR()    asm volatile("s_barrier" ::: "memory")
#define VMBAR(N) asm volatile("s_waitcnt vmcnt(" #N ")\n\ts_barrier" ::: "memory")
#define LGKM0()  asm volatile("s_waitcnt lgkmcnt(0)" ::: "memory")

// ---------------------------------------------------------------------------
// QKV GEMM, 128x256 tile, BK=64, 512 thr = 8 waves (2M x 4N, wave 64x64).
//   C[m][n] = sum_k A[m][k]*W[n][k].  Grid (64, 12) = 768 blocks = EXACTLY
// 3 rounds at 1 block/CU (96 KiB LDS) -> no dispatch tail (R1's 384-block
// 256^2 tiling lost 25% to a half-full second round).
// 2 phases per K-tile split by n-half (8 x mfma_32x32x16 each). B is staged in
// two row-interleaved GROUPS (Bg0 = all waves' nt0 rows {wn*64+[0,32)},
// Bg1 = nt1 rows) so each phase's LDS data is a distinct load group:
//   ph1 reads af(8)+bf0(4), issues A(t+1)+Bg0(t+1);  end: vmcnt(4) [Bg1(t)]
//   ph2 reads bf1(4),       issues Bg1(t+1);         end: vmcnt(2) [A+Bg0(t+1)]
// -> 2..6 loads always in flight, never drained; issue->force >= ~1700 cyc.
// MFMA clusters fenced with sched_barrier(0) + explicit lgkmcnt(0) (rule #18:
// memory clobber alone does not pin register-only MFMAs), setprio(1) inside.
// LDS swizzle: row stride 64 elems, 8 chunks of 16B, pos = chunk ^ (row&7)
// (verified conflict-free scheme from the 128^2 kernel); staging source is
// pre-swizzled so global_load_lds' linear dest matches.
// Grid linear %8 = x%8 -> each m-panel pinned to one XCD's L2.
// sec = y>>2 in {Q,K,V}; V (sec 2) written transposed vt[(b*16+h)*64+d][tok].
// ---------------------------------------------------------------------------
__global__ __launch_bounds__(512, 2) void gemm_qkv(
    const uint16_t* __restrict__ A, const uint16_t* __restrict__ W0,
    uint16_t* __restrict__ C0, uint16_t* __restrict__ vtb)
{
    __shared__ __align__(16) uint16_t As[2][8192];    // 128 x 64 per buf (16 KB)
    __shared__ __align__(16) uint16_t Bs[2][16384];   // 2 grp x 128 x 64 (32 KB)

    const int t = threadIdx.x, lane = t & 63, w = t >> 6;
    const int wm = w >> 2, wn = w & 3;                // 2 x 4 wave grid
    const int ml = lane & 31, half = lane >> 5;

    const int m0  = blockIdx.x * 128;
    const int sec = blockIdx.y >> 2;                  // 0=Q 1=K 2=V
    const int n0  = (blockIdx.y & 3) * 256;
    const uint16_t* __restrict__ Wp = W0 + (size_t)sec * 1048576;

    // staging addresses: set = 512 thr x 16B = 8 KB = 64 rows
    const int srow = t >> 3;                          // row-in-set
    const int sg   = (t & 7) ^ (srow & 7);            // pre-swizzled chunk
    const size_t aOff = (size_t)(m0 + srow) * DIMD + sg * 8;
    size_t bOff[2];
    #pragma unroll
    for (int j = 0; j < 2; ++j)                       // group-row i = j*64+srow
        bOff[j] = (size_t)(n0 + (j*2 + (srow >> 5))*64 + (srow & 31)) * DIMD + sg * 8;
    const int slot = w * 512;                         // wave-uniform LDS base

#define SA(j_, buf_, kk_)  asyncLoad16(A  + aOff + (size_t)(j_)*64*DIMD + (kk_),   \
                                       &As[buf_][(j_)*4096 + slot])
#define SBG(g_, j_, buf_, kk_) asyncLoad16(Wp + bOff[j_] + (size_t)(g_)*32*DIMD + (kk_), \
                                       &Bs[buf_][(g_)*8192 + (j_)*4096 + slot])

    // ---- prologue: tile 0; FIFO order A,A,Bg0,Bg0,Bg1,Bg1 matches steady state
    SA(0,0,0); SA(1,0,0);
    SBG(0,0,0,0); SBG(0,1,0,0);
    SBG(1,0,0,0); SBG(1,1,0,0);
    VMBAR(2);                       // force A + Bg0 of tile 0; Bg1 in flight

    // per-thread constant LDS read offsets
    int pos8[4];
    #pragma unroll
    for (int s = 0; s < 4; ++s) pos8[s] = ((s*2 + half) ^ (ml & 7)) * 8;
    const int arowOff = (wm*64 + ml) * 64;            // + mt*2048
    const int browOff = (wn*32 + ml) * 64;            // + nt*8192

    f32x16 acc[2][2] = {};

    #pragma unroll 2
    for (int kt = 0; kt < 8; ++kt) {                  // K = 8 tiles of 128? no:
        // NOTE: K=1024, BK=64 -> 16 K-tiles; loop body below does ONE K-tile,
        // so iterate 16 times. (kt loop rewritten below with 16 trips.)
        (void)kt; break;
    }

    #pragma unroll 2
    for (int kt = 0; kt < 16; ++kt) {
        const int cur = kt & 1, nxt = cur ^ 1;
        const int k1 = (kt + 1) * 64;
        const bool pf = (kt + 1 < 16);
        const uint16_t* __restrict__ Ac = As[cur];
        const uint16_t* __restrict__ Bc = Bs[cur];

        // ================= phase 1 : n-half 0 =================
        bf16x8 af[2][4], bfn[4];
        #pragma unroll
        for (int s = 0; s < 4; ++s) {
            af[0][s] = *(const bf16x8*)(Ac + arowOff +        pos8[s]);
            af[1][s] = *(const bf16x8*)(Ac + arowOff + 2048 + pos8[s]);
            bfn[s]   = *(const bf16x8*)(Bc + browOff +        pos8[s]);
        }
        if (pf) { SA(0,nxt,k1); SA(1,nxt,k1); SBG(0,0,nxt,k1); SBG(0,1,nxt,k1); }
        BAR();
        LGKM0();
        __builtin_amdgcn_sched_barrier(0);
        __builtin_amdgcn_s_setprio(1);
        #pragma unroll
        for (int s = 0; s < 4; ++s) {
            acc[0][0] = __builtin_amdgcn_mfma_f32_32x32x16_bf16(af[0][s], bfn[s], acc[0][0], 0,0,0);
            acc[1][0] = __builtin_amdgcn_mfma_f32_32x32x16_bf16(af[1][s], bfn[s], acc[1][0], 0,0,0);
        }
        __builtin_amdgcn_s_setprio(0);
        __builtin_amdgcn_sched_barrier(0);
        if (pf) { VMBAR(4); } else { VMBAR(0); }   // force Bg1(t)

        // ================= phase 2 : n-half 1 =================
        #pragma unroll
        for (int s = 0; s < 4; ++s)
            bfn[s] = *(const bf16x8*)(Bc + 8192 + browOff + pos8[s]);
        if (pf) { SBG(1,0,nxt,k1); SBG(1,1,nxt,k1); }
        BAR();
        LGKM0();
        __builtin_amdgcn_sched_barrier(0);
        __builtin_amdgcn_s_setprio(1);
        #pragma unroll
        for (int s = 0; s < 4; ++s) {
            acc[0][1] = __builtin_amdgcn_mfma_f32_32x32x16_bf16(af[0][s], bfn[s], acc[0][1], 0,0,0);
            acc[1][1] = __builtin_amdgcn_mfma_f32_32x32x16_bf16(af[1][s], bfn[s], acc[1][1], 0,0,0);
        }
        __builtin_amdgcn_s_setprio(0);
        __builtin_amdgcn_sched_barrier(0);
        if (pf) { VMBAR(2); }                      // force A + Bg0 of t+1
    }

#undef SA
#undef SBG

    // ---- epilogue: C/D 32x32 layout col=lane&31, row=(r&3)+8*(r>>2)+4*half ----
    if (sec == 2) {
        #pragma unroll
        for (int mt = 0; mt < 2; ++mt)
            #pragma unroll
            for (int nt = 0; nt < 2; ++nt) {
                int colg = n0 + wn*64 + nt*32 + ml;              // dim
                int hh = colg >> 6, dd = colg & 63;
                #pragma unroll
                for (int g = 0; g < 4; ++g) {
                    int rowg = m0 + wm*64 + mt*32 + 8*g + 4*half; // token (+reg&3)
                    int bb = rowg >> 11, nn = rowg & 2047;
                    ushort4 o4;
                    o4.x = f2bf(acc[mt][nt][4*g + 0]);
                    o4.y = f2bf(acc[mt][nt][4*g + 1]);
                    o4.z = f2bf(acc[mt][nt][4*g + 2]);
                    o4.w = f2bf(acc[mt][nt][4*g + 3]);
                    *(ushort4*)(vtb + ((size_t)((bb*NH + hh)*HD + dd))*Nseq + nn) = o4;
                }
            }
    } else {
        uint16_t* C = C0 + (size_t)sec * 8388608;
        #pragma unroll
        for (int mt = 0; mt < 2; ++mt)
            #pragma unroll
            for (int nt = 0; nt < 2; ++nt) {
                int col = n0 + wn*64 + nt*32 + ml;
                #pragma unroll
                for (int r = 0; r < 16; ++r) {
                    int row = m0 + wm*64 + mt*32 + (r & 3) + 8*(r >> 2) + 4*half;
                    C[(size_t)row * DIMD + col] = f2bf(acc[mt][nt][r]);
                }
            }
    }
}

// ---------------------------------------------------------------------------
// GEMM  C[m][n] = sum_k A[m][k] * W[n][k]   (B^T layout, both row-major over K)
// 128x128 tile, BK=64, 256 thr = 4 waves (2x2) -- retained for the output
// projection (N=1024; 512 blocks at ~4 blocks/CU).
// ---------------------------------------------------------------------------
template <typename OutT>
__global__ __launch_bounds__(256) void gemm_bt(
    const uint16_t* __restrict__ A, const uint16_t* __restrict__ W0,
    OutT* __restrict__ C0, int K, int Nld, int blocksPerSec,
    size_t wSecStride, size_t cSecStride, uint16_t* __restrict__ vtb, int vSec)
{
    __shared__ __align__(16) uint16_t As[128*64];
    __shared__ __align__(16) uint16_t Bs[128*64];

    const int t = threadIdx.x, lane = t & 63, w = t >> 6;
    const int wr = w >> 1, wc = w & 1;
    const int half = lane >> 5, ml = lane & 31;

    const int m0  = blockIdx.x * 128;
    const int sec = blockIdx.y / blocksPerSec;
    const int n0  = (blockIdx.y % blocksPerSec) * 128;
    const uint16_t* Wp = W0 + (size_t)sec * wSecStride;
    OutT* C = C0 + (size_t)sec * cSecStride;

    int srow[4], sg[4];
    #pragma unroll
    for (int i = 0; i < 4; ++i) {
        int s = t + 256*i;
        srow[i] = s >> 3;
        sg[i]   = (s & 7) ^ (srow[i] & 7);
    }

    int arow[2], brow[2];
    #pragma unroll
    for (int i = 0; i < 2; ++i) {
        arow[i] = wr*64 + i*32 + ml;
        brow[i] = wc*64 + i*32 + ml;
    }

    f32x16 acc[2][2] = {};

    for (int k0 = 0; k0 < K; k0 += 64) {
        __syncthreads();
        #pragma unroll
        for (int i = 0; i < 4; ++i) {
            asyncLoad16(A  + (size_t)(m0 + srow[i])*K + k0 + sg[i]*8,
                        As + (size_t)(w*64 + 256*i)*8);
            asyncLoad16(Wp + (size_t)(n0 + srow[i])*K + k0 + sg[i]*8,
                        Bs + (size_t)(w*64 + 256*i)*8);
        }
        __syncthreads();

        #pragma unroll
        for (int s = 0; s < 4; ++s) {            // k-step of 16
            const int chunk = s*2 + half;
            bf16x8 af[2], bfr[2];
            #pragma unroll
            for (int i = 0; i < 2; ++i) {
                int m = arow[i];
                af[i]  = *(const bf16x8*)(As + (size_t)(m*8 + (chunk ^ (m & 7)))*8);
                int n = brow[i];
                bfr[i] = *(const bf16x8*)(Bs + (size_t)(n*8 + (chunk ^ (n & 7)))*8);
            }
            #pragma unroll
            for (int mt = 0; mt < 2; ++mt)
                #pragma unroll
                for (int nt = 0; nt < 2; ++nt)
                    acc[mt][nt] = __builtin_amdgcn_mfma_f32_32x32x16_bf16(
                        af[mt], bfr[nt], acc[mt][nt], 0, 0, 0);
        }
    }

    if (vtb != nullptr && sec == vSec) {
        #pragma unroll
        for (int mt = 0; mt < 2; ++mt)
            #pragma unroll
            for (int nt = 0; nt < 2; ++nt) {
                int colg = n0 + wc*64 + nt*32 + ml;               // dim
                int hh = colg >> 6, dd = colg & 63;
                #pragma unroll
                for (int g = 0; g < 4; ++g) {
                    int rowg = m0 + wr*64 + mt*32 + 8*g + 4*half; // token (+reg&3)
                    int bb = rowg >> 11, nn = rowg & 2047;
                    ushort4 o4;
                    o4.x = f2bf(acc[mt][nt][4*g + 0]);
                    o4.y = f2bf(acc[mt][nt][4*g + 1]);
                    o4.z = f2bf(acc[mt][nt][4*g + 2]);
                    o4.w = f2bf(acc[mt][nt][4*g + 3]);
                    *(ushort4*)(vtb + ((size_t)((bb*NH + hh)*HD + dd))*Nseq + nn) = o4;
                }
            }
    } else {
        #pragma unroll
        for (int mt = 0; mt < 2; ++mt)
            #pragma unroll
            for (int nt = 0; nt < 2; ++nt) {
                int col = n0 + wc*64 + nt*32 + ml;
                #pragma unroll
                for (int r = 0; r < 16; ++r) {
                    int row = m0 + wr*64 + mt*32 + (r & 3) + 8*(r >> 2) + 4*half;
                    storeOut(&C[(size_t)row * Nld + col], acc[mt][nt][r]);
                }
            }
    }
}

// ---------------------------------------------------------------------------
// Flash attention, causal, no-max online softmax, S^T formulation:
//   S^T = K.Q^T  -> P^T in registers is the B-operand of mfma 16x16x16bf16_1k
//   -> O^T = V^T.P^T, no P LDS round-trip.
// ---------------------------------------------------------------------------
__global__ __launch_bounds__(256, 4) void attn(
    const uint16_t* __restrict__ Q, const uint16_t* __restrict__ K,
    const uint16_t* __restrict__ Vt, uint16_t* __restrict__ O)
{
    __shared__ __align__(16) uint16_t Kb[2][64*64];   // 16 KB (also Q scratch)
    __shared__ __align__(16) uint16_t Vb[2][64*64];   // 16 KB (V^T tiles, rows=d)

    const int t = threadIdx.x, lane = t & 63, w = t >> 6;
    const int quad = lane >> 4, c = lane & 15;
    const int y = blockIdx.y;
    const int qi = (y < 4) ? (15 - y) : (y < 8) ? (y + 4) : (y < 12) ? (y - 4) : (15 - y);
    const int q0 = qi * 128;
    const int bh = blockIdx.x, b = bh >> 4, h = bh & 15;
    const size_t tokBase = (size_t)b * Nseq;
    const int hcol = h * HD;
    uint16_t* Qs = (uint16_t*)Kb;                    // 16 KB scratch

    #define STAGE_KV(k0_, buf_)                                             \
        _Pragma("unroll")                                                    \
        for (int i = 0; i < 2; ++i) {                                        \
            int s = t + 256*i;                                               \
            int row = s >> 3, gg = (s & 7) ^ (row & 7);                      \
            asyncLoad16(K + (tokBase + (k0_) + row)*DIMD + hcol + gg*8,      \
                        Kb[buf_] + (size_t)(w*64 + 256*i)*8);                \
            asyncLoad16(Vt + ((size_t)bh*HD + row)*Nseq + (k0_) + gg*8,      \
                        Vb[buf_] + (size_t)(w*64 + 256*i)*8);                \
        }

    // ---- stage Q (128x64) through scratch, grab fragments, then free it ----
    #pragma unroll
    for (int i = 0; i < 4; ++i) {
        int s = t + 256*i;
        int row = s >> 3, gg = (s & 7) ^ (row & 7);
        asyncLoad16(Q + (tokBase + q0 + row)*DIMD + hcol + gg*8,
                    Qs + (size_t)(w*64 + 256*i)*8);
    }
    __syncthreads();                                  // Q landed
    bf16x8 qf[2][2];
    #pragma unroll
    for (int qt = 0; qt < 2; ++qt)
        #pragma unroll
        for (int ks = 0; ks < 2; ++ks) {
            int row = w*32 + qt*16 + c;
            int pos = (ks*4 + quad) ^ (row & 7);
            qf[qt][ks] = *(const bf16x8*)(Qs + (size_t)(row*8 + pos)*8);
        }
    __syncthreads();                                  // all reads done, scratch free
    STAGE_KV(0, 0);

    const int wrow0 = q0 + w*32;
    const int end = 2*qi + 2;
    f32x4  o[2][4] = {};
    float  l_lane[2] = {0.f, 0.f};

    for (int kt = 0; kt < end; ++kt) {
        const int cur = kt & 1, nxt = cur ^ 1;
        const int k0 = kt * 64;
        __syncthreads();              // buf[cur] ready; buf[nxt] free to fill

        if (kt + 1 < end) { STAGE_KV((kt+1)*64, nxt); }

        if (k0 > wrow0 + 31) continue;     // wave fully above diagonal

        const uint16_t* Ks = Kb[cur];
        const uint16_t* Vs = Vb[cur];

        // ---- S^T = K.Q^T : C-layout row = kv (quad*4+r), col = q (c) ----
        f32x4 sv[2][4] = {};
        #pragma unroll
        for (int nt = 0; nt < 4; ++nt)
            #pragma unroll
            for (int ks = 0; ks < 2; ++ks) {
                int row = nt*16 + c;
                int pos = (ks*4 + quad) ^ (row & 7);
                bf16x8 kf = *(const bf16x8*)(Ks + (size_t)(row*8 + pos)*8);
                sv[0][nt] = __builtin_amdgcn_mfma_f32_16x16x32_bf16(kf, qf[0][ks], sv[0][nt], 0, 0, 0);
                sv[1][nt] = __builtin_amdgcn_mfma_f32_16x16x32_bf16(kf, qf[1][ks], sv[1][nt], 0, 0, 0);
            }

        // ---- causal mask (diagonal tiles only; kv > q -> -inf) ----
        if (k0 + 63 > wrow0) {
            #pragma unroll
            for (int qt = 0; qt < 2; ++qt)
                #pragma unroll
                for (int nt = 0; nt < 4; ++nt)
                    #pragma unroll
                    for (int r = 0; r < 4; ++r) {
                        int kvg = k0 + nt*16 + quad*4 + r;
                        int qg  = wrow0 + qt*16 + c;
                        if (kvg > qg) sv[qt][nt][r] = -340.0f;
                    }
        }

        // ---- p = exp2(s); row-sum per lane; pack P^T as B-frags ----
        s16x4 pb[2][4];
        #pragma unroll
        for (int qt = 0; qt < 2; ++qt)
            #pragma unroll
            for (int nt = 0; nt < 4; ++nt) {
                float p0 = __builtin_amdgcn_exp2f(sv[qt][nt][0]);
                float p1 = __builtin_amdgcn_exp2f(sv[qt][nt][1]);
                float p2 = __builtin_amdgcn_exp2f(sv[qt][nt][2]);
                float p3 = __builtin_amdgcn_exp2f(sv[qt][nt][3]);
                l_lane[qt] += (p0 + p1) + (p2 + p3);
                union { uint32_t u[2]; s16x4 v; } pu;
                pu.u[0] = pk2(p0, p1);
                pu.u[1] = pk2(p2, p3);
                pb[qt][nt] = pu.v;
            }

        // ---- O^T += V^T.P^T  (K=16 steps; A=V^T rows from LDS b64) ----
        #pragma unroll
        for (int s4 = 0; s4 < 4; ++s4)
            #pragma unroll
            for (int dt = 0; dt < 4; ++dt) {
                int row = dt*16 + c;                    // d
                int chunk = s4*2 + (quad >> 1);
                int pos = chunk ^ (row & 7);
                s16x4 vf = *(const s16x4*)(Vs + (size_t)(row*8 + pos)*8 + (quad & 1)*4);
                o[0][dt] = __builtin_amdgcn_mfma_f32_16x16x16bf16_1k(vf, pb[0][s4], o[0][dt], 0, 0, 0);
                o[1][dt] = __builtin_amdgcn_mfma_f32_16x16x16bf16_1k(vf, pb[1][s4], o[1][dt], 0, 0, 0);
            }
    }

    // ---- epilogue: reduce l over quads, scale, store O^T packed ----
    #pragma unroll
    for (int qt = 0; qt < 2; ++qt) {
        float l = l_lane[qt];
        l += __shfl_xor(l, 16);
        l += __shfl_xor(l, 32);
        float inv = 1.0f / l;
        int tok = (int)(q0 + w*32 + qt*16 + c);
        #pragma unroll
        for (int dt = 0; dt < 4; ++dt) {
            ushort4 o4;
            o4.x = f2bf(o[qt][dt][0] * inv);
            o4.y = f2bf(o[qt][dt][1] * inv);
            o4.z = f2bf(o[qt][dt][2] * inv);
            o4.w = f2bf(o[qt][dt][3] * inv);
            *(ushort4*)(O + (tokBase + tok)*DIMD + hcol + dt*16 + quad*4) = o4;
        }
    }
    #undef STAGE_KV
}

// ---------------------------------------------------------------------------
extern "C" void kernel_launch(void* const* d_in, const int* in_sizes, int n_in,
                              void* d_out, int out_size, void* d_ws, size_t ws_size,
                              hipStream_t stream) {
    const float* x  = (const float*)d_in[0];
    // d_in[1] = causal tril mask, deterministic -> handled analytically
    const float* Wq = (const float*)d_in[2];
    const float* Wk = (const float*)d_in[3];
    const float* Wv = (const float*)d_in[4];
    const float* Wo = (const float*)d_in[5];

    uint16_t* ws  = (uint16_t*)d_ws;
    uint16_t* xb  = ws;                      // x bf16 (later reused as attn out)
    uint16_t* wqb = ws + 8388608;            // Wq,Wk,Wv,Wo bf16 contiguous
    uint16_t* wob = wqb + 3*1048576;
    uint16_t* qb  = ws + 12582912;           // Q
    uint16_t* kb  = qb + 8388608;            // K
    uint16_t* vtb = kb + 8388608;            // V transposed per (b,h)
    uint16_t* ab  = xb;                      // attention output reuses xb

    cast_all<<<12288, 256, 0, stream>>>(x, Wq, Wk, Wv, Wo, ws);

    // QKV: 128x256 2-phase counted-vmcnt kernel; 768 blocks = 3 clean rounds.
    gemm_qkv<<<dim3(64, 12), 512, 0, stream>>>(xb, wqb, qb, vtb);

    attn<<<dim3(64, 16), 256, 0, stream>>>(qb, kb, vtb, ab);

    gemm_bt<float><<<dim3(64, 8), 256, 0, stream>>>(
        ab, wob, (float*)d_out, DIMD, DIMD, 8, (size_t)0, (size_t)0, nullptr, -1);
}